// Round 7
// baseline (278.745 us; speedup 1.0000x reference)
//
#include <hip/hip_runtime.h>
#include <cmath>

#define TPB 256

static const int NTOK  = 1025;
static const int DIM   = 768;
static const int HEADS = 12;
static const int QK3   = 2304;
static const int ROWS  = 4 * NTOK;        // 4100
static const int MROWS = 4 * (NTOK - 1);  // 4096
static const int MPAD  = 4224;            // 33*128 padded A rows
static const int NPAD  = 1088;            // 17*64
static const int VROWS = 129;             // 128 V cols + 1 ones-row (l column)
static const size_t OUT0 = (size_t)ROWS * DIM;
static const size_t APLANE = (size_t)MPAD * DIM;   // bf16 per plane

// workspace offsets in floats (qkv/qkvm bf16)
static const size_t OFF_QKV16  = 0;          // 4100*2304 u16 = 4,723,200 f
static const size_t OFF_QKVM16 = 4800000;    // 4096*2304 u16 = 4,718,592 f
static const size_t OFF_QE     = 9600000;    // 48*1088*64 u16 = 1,671,168 f
static const size_t OFF_KE     = 11300000;   // 1,671,168 f
static const size_t OFF_VT     = 13000000;   // 48*129*1088 u16 = 3,368,448 f
static const size_t OFF_ABF    = 16400000;   // 2*4224*768 u16 = 3,244,032 f
static const size_t OFF_WQ     = 19700000;   // 2*2304*768 u16 = 1,769,472 f
static const size_t OFF_WO     = 21500000;   // 2*768*768 u16  =   589,824 f
static const size_t OFF_CMAX   = 22100000;   // 9,216 f
static const size_t OFF_UPD    = 22110000;   // 4,100 f
// k_attn ones-group staging reads vt rows 129..143 of the last bh: lands in
// the VT->ABF gap (mapped, finite poison); those acc rows are never used.

typedef __attribute__((ext_vector_type(8))) short short8;
typedef __attribute__((ext_vector_type(4))) float f32x4;

__device__ __forceinline__ unsigned short f2bf(float f) {
    union { float f; unsigned int u; } c; c.f = f;
    unsigned int u = c.u + 0x7fffu + ((c.u >> 16) & 1u);  // RNE
    return (unsigned short)(u >> 16);
}
__device__ __forceinline__ float bf2f(unsigned short u) {
    union { unsigned int u; float f; } c; c.u = (unsigned int)u << 16;
    return c.f;
}
__device__ __forceinline__ void gl_lds16(const unsigned short* g, unsigned short* l) {
    __builtin_amdgcn_global_load_lds(
        (const __attribute__((address_space(1))) unsigned int*)g,
        (__attribute__((address_space(3))) unsigned int*)l, 16, 0, 0);
}

// ---------------------------------------------------------------------------
// K0: fp32 -> bf16 conversions (unchanged)
// ---------------------------------------------------------------------------
__global__ __launch_bounds__(TPB)
void k_cvt(const float* __restrict__ x, const float* __restrict__ mask,
           const float* __restrict__ wqkv, const float* __restrict__ wout,
           unsigned short* __restrict__ Abf, unsigned short* __restrict__ Wq,
           unsigned short* __restrict__ Wo)
{
    const int z = blockIdx.z;
    const size_t idx = ((size_t)blockIdx.x * TPB + threadIdx.x) * 8;
    unsigned short o[8] __attribute__((aligned(16)));
    if (z <= 1) {
        if (idx >= APLANE) return;
        const int row = (int)(idx / DIM);
        const int M = z ? MROWS : ROWS;
        const float* src = z ? mask : x;
        if (row < M) {
            float a[8];
            *(float4*)&a[0] = *(const float4*)(src + idx);
            *(float4*)&a[4] = *(const float4*)(src + idx + 4);
#pragma unroll
            for (int i = 0; i < 8; ++i) o[i] = f2bf(a[i]);
        } else {
#pragma unroll
            for (int i = 0; i < 8; ++i) o[i] = 0;
        }
        *(short8*)(Abf + (size_t)z * APLANE + idx) = *(short8*)o;
    } else {
        const size_t tot = (z == 2) ? (size_t)QK3 * DIM : (size_t)DIM * DIM;
        if (idx >= tot) return;
        const float* src = (z == 2) ? wqkv : wout;
        unsigned short* dst = (z == 2) ? Wq : Wo;
        float a[8];
        *(float4*)&a[0] = *(const float4*)(src + idx);
        *(float4*)&a[4] = *(const float4*)(src + idx + 4);
        unsigned short oa[8] __attribute__((aligned(16)));
#pragma unroll
        for (int i = 0; i < 8; ++i) { o[i] = f2bf(a[i]); oa[i] = f2bf(fabsf(a[i])); }
        *(short8*)(dst + idx) = *(short8*)o;
        *(short8*)(dst + tot + idx) = *(short8*)oa;
    }
}

// ---------------------------------------------------------------------------
// K1: bf16 MFMA GEMM, BK=64, bf16 C, fused col-max (unchanged)
// ---------------------------------------------------------------------------
__global__ __launch_bounds__(TPB)
void k_gemm_qkv_mfma(const unsigned short* __restrict__ Abf,
                     const unsigned short* __restrict__ Wq,
                     unsigned short* __restrict__ qkv16,
                     unsigned short* __restrict__ qkvm16,
                     float* __restrict__ cmax)
{
    const int z = blockIdx.z;
    const int rowT = blockIdx.y * 128, colT = blockIdx.x * 128;
    if (z == 1 && rowT >= MROWS) return;
    const unsigned short* A = Abf + (size_t)z * APLANE;
    const unsigned short* B = Wq + (size_t)z * QK3 * DIM;

    __shared__ unsigned short As[128 * 64];
    __shared__ unsigned short Bs[128 * 64];

    const int t = threadIdx.x;
    const int w = t >> 6, lane = t & 63, l15 = lane & 15, quad = lane >> 4;
    const int wm = (w & 1) * 64, wn = (w >> 1) * 64;
    const int sr = t >> 2, sk = (t & 3) * 8;

    f32x4 acc[4][4];
#pragma unroll
    for (int i = 0; i < 4; ++i)
#pragma unroll
        for (int j = 0; j < 4; ++j) acc[i][j] = (f32x4){0.f, 0.f, 0.f, 0.f};

    for (int k0 = 0; k0 < DIM; k0 += 64) {
        __syncthreads();
#pragma unroll
        for (int c = 0; c < 4; ++c) {
            const int gr = sr + (c & 1) * 64;
            const int gk = k0 + (c >> 1) * 32 + sk;
            gl_lds16(A + (size_t)(rowT + gr) * DIM + gk, As + c * 2048 + t * 8);
            gl_lds16(B + (size_t)(colT + gr) * DIM + gk, Bs + c * 2048 + t * 8);
        }
        __syncthreads();
        short8 fa[2][4], fb[2][4];
#pragma unroll
        for (int kk = 0; kk < 2; ++kk) {
#pragma unroll
            for (int mi = 0; mi < 4; ++mi)
                fa[kk][mi] = *(const short8*)(As + kk * 4096 + (wm + mi * 16 + l15) * 32 + quad * 8);
#pragma unroll
            for (int ni = 0; ni < 4; ++ni)
                fb[kk][ni] = *(const short8*)(Bs + kk * 4096 + (wn + ni * 16 + l15) * 32 + quad * 8);
        }
#pragma unroll
        for (int kk = 0; kk < 2; ++kk)
#pragma unroll
            for (int mi = 0; mi < 4; ++mi)
#pragma unroll
                for (int ni = 0; ni < 4; ++ni)
                    acc[mi][ni] = __builtin_amdgcn_mfma_f32_16x16x32_bf16(fa[kk][mi], fb[kk][ni], acc[mi][ni], 0, 0, 0);
    }

    float cm[4] = {0.f, 0.f, 0.f, 0.f};
#pragma unroll
    for (int mi = 0; mi < 4; ++mi)
#pragma unroll
        for (int ni = 0; ni < 4; ++ni) {
            const int col = colT + wn + ni * 16 + l15;
#pragma unroll
            for (int r = 0; r < 4; ++r) {
                const int row = rowT + wm + mi * 16 + quad * 4 + r;
                const float v = acc[mi][ni][r];
                if (z == 0) {
                    if (row < ROWS) qkv16[(size_t)row * QK3 + col] = f2bf(v);
                } else {
                    qkvm16[(size_t)row * QK3 + col] = f2bf(v);
                    cm[ni] = fmaxf(cm[ni], v);
                }
            }
        }
    if (z == 1) {
        const int bb = rowT >> 10;
#pragma unroll
        for (int ni = 0; ni < 4; ++ni) {
            float m = cm[ni];
            m = fmaxf(m, __shfl_xor(m, 16, 64));
            m = fmaxf(m, __shfl_xor(m, 32, 64));
            if (quad == 0)
                atomicMax((int*)&cmax[bb * QK3 + colT + wn + ni * 16 + l15], __float_as_int(m));
        }
    }
}

// ---------------------------------------------------------------------------
// K2: merged small kernels (unchanged)
// ---------------------------------------------------------------------------
__global__ __launch_bounds__(TPB)
void k_misc(const float* __restrict__ mask, float* __restrict__ upd,
            unsigned short* __restrict__ vt)
{
    const int bx = blockIdx.x;
    if (bx >= 1025) {
        const int bh = bx - 1025;
        unsigned short* p = vt + ((size_t)bh * VROWS + 128) * NPAD;
        for (int n = threadIdx.x; n < NPAD; n += TPB)
            p[n] = (n < NTOK) ? (unsigned short)0x3F80 : (unsigned short)0;
        return;
    }
    const int w = threadIdx.x >> 6, lane = threadIdx.x & 63;
    const int r = bx * 4 + w;
    if (r >= ROWS) return;
    const int b = r / NTOK, n = r % NTOK;
    float res = 1.f;
    if (n > 0) {
        const float* p = mask + (size_t)(b * (NTOK - 1) + (n - 1)) * DIM;
        float s = 0.f;
        for (int i = lane; i < DIM; i += 64) s += p[i];
#pragma unroll
        for (int off = 32; off > 0; off >>= 1) s += __shfl_xor(s, off, 64);
        res = (s > 0.f) ? 1.f : 0.f;
    }
    if (lane == 0) upd[r] = res;
}

// ---------------------------------------------------------------------------
// K3: qe/ke bf16 [bh,1088,64], vt bf16 transposed [bh,129,1088] (unchanged)
// ---------------------------------------------------------------------------
__global__ __launch_bounds__(TPB)
void k_prep(const unsigned short* __restrict__ qkv16,
            const unsigned short* __restrict__ qkvm16,
            const float* __restrict__ cmax, unsigned short* __restrict__ qe,
            unsigned short* __restrict__ ke, unsigned short* __restrict__ vt)
{
    __shared__ unsigned short Vt_l[128 * 66];
    const int t = threadIdx.x;
    const int nt = blockIdx.x, h = blockIdx.y, b = blockIdx.z;
    const int bh = b * HEADS + h;
    const int nl = t >> 2, ds0 = (t & 3) * 16;
    const int n = nt * 64 + nl;
    const bool valid = n < NTOK;
    const int col0 = h * 64 + ds0;

    unsigned short q16[16] __attribute__((aligned(16))) = {0};
    unsigned short k16[16] __attribute__((aligned(16))) = {0};
    unsigned short v16[16] __attribute__((aligned(16))) = {0};
    unsigned short qm16[16] __attribute__((aligned(16)));
    unsigned short km16[16] __attribute__((aligned(16)));
    unsigned short vm16[16] __attribute__((aligned(16)));
    float cq[16], ck[16], cv[16];

    const bool useM = valid && (n > 0);
    if (valid) {
        const size_t br = (size_t)(b * NTOK + n) * QK3 + col0;
        *(short8*)&q16[0] = *(const short8*)(qkv16 + br);
        *(short8*)&q16[8] = *(const short8*)(qkv16 + br + 8);
        *(short8*)&k16[0] = *(const short8*)(qkv16 + br + 768);
        *(short8*)&k16[8] = *(const short8*)(qkv16 + br + 776);
        *(short8*)&v16[0] = *(const short8*)(qkv16 + br + 1536);
        *(short8*)&v16[8] = *(const short8*)(qkv16 + br + 1544);
    }
    if (useM) {
        const size_t mr = (size_t)(b * 1024 + (n - 1)) * QK3 + col0;
        *(short8*)&qm16[0] = *(const short8*)(qkvm16 + mr);
        *(short8*)&qm16[8] = *(const short8*)(qkvm16 + mr + 8);
        *(short8*)&km16[0] = *(const short8*)(qkvm16 + mr + 768);
        *(short8*)&km16[8] = *(const short8*)(qkvm16 + mr + 776);
        *(short8*)&vm16[0] = *(const short8*)(qkvm16 + mr + 1536);
        *(short8*)&vm16[8] = *(const short8*)(qkvm16 + mr + 1544);
        const int cb = b * QK3 + col0;
#pragma unroll
        for (int i = 0; i < 4; ++i) {
            *(float4*)&cq[i * 4] = *(const float4*)(cmax + cb + i * 4);
            *(float4*)&ck[i * 4] = *(const float4*)(cmax + cb + 768 + i * 4);
            *(float4*)&cv[i * 4] = *(const float4*)(cmax + cb + 1536 + i * 4);
        }
    }

    unsigned short oq[16] __attribute__((aligned(16)));
    unsigned short ok[16] __attribute__((aligned(16)));
#pragma unroll
    for (int idx = 0; idx < 16; ++idx) {
        const float qm = useM ? bf2f(qm16[idx]) / (1e-6f + cq[idx]) : 1.f;
        const float km = useM ? bf2f(km16[idx]) / (1e-6f + ck[idx]) : 1.f;
        const float vm = valid ? (useM ? bf2f(vm16[idx]) / (1e-6f + cv[idx]) : 1.f) : 0.f;
        oq[idx] = f2bf(bf2f(q16[idx]) * qm * 0.125f);
        ok[idx] = f2bf(bf2f(k16[idx]) * km);
        const int d = ds0 + idx;
        Vt_l[d * 66 + nl]        = f2bf(bf2f(v16[idx]) * vm);
        Vt_l[(64 + d) * 66 + nl] = f2bf(vm);
    }
    if (valid) {
        unsigned short* qp = qe + ((size_t)bh * NPAD + n) * 64 + ds0;
        unsigned short* kp = ke + ((size_t)bh * NPAD + n) * 64 + ds0;
        *(short8*)qp       = *(short8*)oq;
        *(short8*)(qp + 8) = *(short8*)(oq + 8);
        *(short8*)kp       = *(short8*)ok;
        *(short8*)(kp + 8) = *(short8*)(ok + 8);
    }
    __syncthreads();
    const int c = t >> 1, nh = (t & 1) * 32;
    unsigned short ov[32] __attribute__((aligned(16)));
#pragma unroll
    for (int i = 0; i < 32; ++i) ov[i] = Vt_l[c * 66 + nh + i];
    unsigned short* vp = vt + ((size_t)bh * VROWS + c) * NPAD + nt * 64 + nh;
#pragma unroll
    for (int i = 0; i < 4; ++i) *(short8*)(vp + i * 8) = *(short8*)(ov + i * 8);
}

// ---------------------------------------------------------------------------
// K4: MFMA flash attention, operand-swapped, VGPR-prefetch double-buffered
// staging: tile kt+1's K/V fragments are loaded global->VGPR during tile kt's
// compute; barrier -> ds_write -> barrier puts them in LDS with the global
// latency already hidden (the vmcnt wait lands after a full compute phase).
// ---------------------------------------------------------------------------
__global__ __launch_bounds__(TPB)
void k_attn(const unsigned short* __restrict__ qe, const unsigned short* __restrict__ ke,
            const unsigned short* __restrict__ vt, const float* __restrict__ upd,
            unsigned short* __restrict__ ab2)
{
    __shared__ short8 KsF[8 * 64];    // g = kk*4 + nc
    __shared__ short8 VsF[18 * 64];   // g = kk*9 + c8 (c8=8 is the ones-group)

    const int t = threadIdx.x;
    const int w = t >> 6, lane = t & 63;
    const int l15 = lane & 15, quad = lane >> 4;
    const int bh = blockIdx.y;
    const int b = bh / HEADS, h = bh % HEADS;
    const int q0 = blockIdx.x * 64;
    const int qrow = q0 + w * 16 + l15;     // this lane's q (as S^T col)

    short8 qf0, qf1;
    {
        const unsigned short* qp = qe + ((size_t)bh * NPAD + qrow) * 64 + (quad << 3);
        qf0 = *(const short8*)qp;
        qf1 = *(const short8*)(qp + 32);
    }
    const int pA = (quad & 1) * 32 + l15;   // shuffle source lanes
    const int pB = pA + 16;
    const bool lo32 = (lane < 32);

    // prefetch source pointers (lane-fixed parts folded)
    const unsigned short* kpg[2];
#pragma unroll
    for (int gi = 0; gi < 2; ++gi) {
        const int g = 2 * w + gi, kk = g >> 2, nc = g & 3;
        kpg[gi] = ke + ((size_t)bh * NPAD + nc * 16 + l15) * 64 + kk * 32 + (quad << 3);
    }
    const unsigned short* vpg[5];
    const int nv = (w < 2) ? 5 : 4;
#pragma unroll
    for (int i = 0; i < 5; ++i) {
        const int g = w + 4 * i;
        if (g < 18) {
            const int kk = (g >= 9) ? 1 : 0, c8 = g - kk * 9;
            vpg[i] = vt + ((size_t)bh * VROWS + c8 * 16 + l15) * NPAD + kk * 32 + (quad << 3);
        }
    }

    f32x4 acc[9];   // 0..7 = 128 out cols (d), 8 = l column
#pragma unroll
    for (int g = 0; g < 9; ++g) acc[g] = (f32x4){0.f, 0.f, 0.f, 0.f};

    // prefetch tile 0
    short8 kpre[2], vpre[5];
#pragma unroll
    for (int gi = 0; gi < 2; ++gi) kpre[gi] = *(const short8*)(kpg[gi]);
#pragma unroll
    for (int i = 0; i < 5; ++i) if (i < nv) vpre[i] = *(const short8*)(vpg[i] + 0);

    for (int kt = 0; kt < 17; ++kt) {
        __syncthreads();   // all waves done reading previous tile's LDS
#pragma unroll
        for (int gi = 0; gi < 2; ++gi)
            KsF[(2 * w + gi) * 64 + lane] = kpre[gi];
#pragma unroll
        for (int i = 0; i < 5; ++i)
            if (i < nv) VsF[(w + 4 * i) * 64 + lane] = vpre[i];
        __syncthreads();   // staged tile visible

        // issue next tile's global loads (latency hidden under compute below)
        if (kt < 16) {
            const int kn1 = (kt + 1) * 64;
#pragma unroll
            for (int gi = 0; gi < 2; ++gi) kpre[gi] = *(const short8*)(kpg[gi] + (size_t)kn1 * 64);
#pragma unroll
            for (int i = 0; i < 5; ++i)
                if (i < nv) vpre[i] = *(const short8*)(vpg[i] + kn1);
        }

        // S^T: rows kv (quad*4+r within block nc), cols q (l15)
        f32x4 s[4];
#pragma unroll
        for (int nc = 0; nc < 4; ++nc) {
            f32x4 z = (f32x4){0.f, 0.f, 0.f, 0.f};
            z = __builtin_amdgcn_mfma_f32_16x16x32_bf16(KsF[nc * 64 + lane], qf0, z, 0, 0, 0);
            z = __builtin_amdgcn_mfma_f32_16x16x32_bf16(KsF[(4 + nc) * 64 + lane], qf1, z, 0, 0, 0);
            s[nc] = z;
        }
        // p = exp(S - 10): exact softmax after final 1/l
        unsigned int dA[4], dB[4];
#pragma unroll
        for (int nc = 0; nc < 4; ++nc) {
            const float p0 = __expf(s[nc][0] - 10.f);
            const float p1 = __expf(s[nc][1] - 10.f);
            const float p2 = __expf(s[nc][2] - 10.f);
            const float p3 = __expf(s[nc][3] - 10.f);
            dA[nc] = (unsigned int)f2bf(p0) | ((unsigned int)f2bf(p1) << 16);
            dB[nc] = (unsigned int)f2bf(p2) | ((unsigned int)f2bf(p3) << 16);
        }
        // P^T B-frags via register permute
        union { int i[4]; short8 s; } u0, u1;
        {
            const int a0 = __shfl((int)dA[0], pA, 64), a1 = __shfl((int)dA[1], pA, 64);
            const int b0 = __shfl((int)dB[0], pA, 64), b1 = __shfl((int)dB[1], pA, 64);
            const int a2 = __shfl((int)dA[0], pB, 64), a3 = __shfl((int)dA[1], pB, 64);
            const int b2 = __shfl((int)dB[0], pB, 64), b3 = __shfl((int)dB[1], pB, 64);
            u0.i[0] = lo32 ? a0 : a1;
            u0.i[1] = lo32 ? b0 : b1;
            u0.i[2] = lo32 ? a2 : a3;
            u0.i[3] = lo32 ? b2 : b3;
        }
        {
            const int a0 = __shfl((int)dA[2], pA, 64), a1 = __shfl((int)dA[3], pA, 64);
            const int b0 = __shfl((int)dB[2], pA, 64), b1 = __shfl((int)dB[3], pA, 64);
            const int a2 = __shfl((int)dA[2], pB, 64), a3 = __shfl((int)dA[3], pB, 64);
            const int b2 = __shfl((int)dB[2], pB, 64), b3 = __shfl((int)dB[3], pB, 64);
            u1.i[0] = lo32 ? a0 : a1;
            u1.i[1] = lo32 ? b0 : b1;
            u1.i[2] = lo32 ? a2 : a3;
            u1.i[3] = lo32 ? b2 : b3;
        }
        const short8 pf0 = u0.s, pf1 = u1.s;
        // O^T += V^T P^T  (9 independent chains incl. l column)
#pragma unroll
        for (int g = 0; g < 9; ++g) {
            acc[g] = __builtin_amdgcn_mfma_f32_16x16x32_bf16(VsF[g * 64 + lane], pf0, acc[g], 0, 0, 0);
            acc[g] = __builtin_amdgcn_mfma_f32_16x16x32_bf16(VsF[(9 + g) * 64 + lane], pf1, acc[g], 0, 0, 0);
        }
    }

    // l(q) sits at quad==0, reg 0 of acc[8], lane l15 = q
    const float lq = __shfl(acc[8][0], l15, 64);
    if (qrow < NTOK) {
        const size_t rg = (size_t)b * NTOK + qrow;
        const float inv = upd[rg] / lq;
#pragma unroll
        for (int g = 0; g < 8; ++g) {
            uint2 pk;
            pk.x = (unsigned int)f2bf(acc[g][0] * inv) | ((unsigned int)f2bf(acc[g][1] * inv) << 16);
            pk.y = (unsigned int)f2bf(acc[g][2] * inv) | ((unsigned int)f2bf(acc[g][3] * inv) << 16);
            const size_t addr = (size_t)(g >> 2) * APLANE + rg * DIM + h * 64 + (g & 3) * 16 + quad * 4;
            *(uint2*)(ab2 + addr) = pk;
        }
    }
}

// ---------------------------------------------------------------------------
// K5: bf16 MFMA out-GEMMs (unchanged)
// ---------------------------------------------------------------------------
__global__ __launch_bounds__(TPB)
void k_gemm_out_mfma(const unsigned short* __restrict__ ab2,
                     const unsigned short* __restrict__ Wo,
                     const float* __restrict__ bout, float* __restrict__ dout)
{
    const int z = blockIdx.z;
    const unsigned short* A = ab2 + (size_t)z * APLANE;
    const unsigned short* B = Wo + (size_t)z * DIM * DIM;

    __shared__ unsigned short As[128 * 32];
    __shared__ unsigned short Bs[128 * 32];

    const int t = threadIdx.x;
    const int w = t >> 6, lane = t & 63, l15 = lane & 15, quad = lane >> 4;
    const int rowT = blockIdx.y * 128, colT = blockIdx.x * 128;
    const int wm = (w & 1) * 64, wn = (w >> 1) * 64;

    const int r0 = t >> 2, kc = (t & 3) * 8;
    const unsigned short* Ap = A + (size_t)(rowT + r0) * DIM + kc;
    const unsigned short* Bp = B + (size_t)(colT + r0) * DIM + kc;

    f32x4 acc[4][4];
#pragma unroll
    for (int i = 0; i < 4; ++i)
#pragma unroll
        for (int j = 0; j < 4; ++j) acc[i][j] = (f32x4){0.f, 0.f, 0.f, 0.f};

    for (int k0 = 0; k0 < DIM; k0 += 32) {
        __syncthreads();
        gl_lds16(Ap + k0,            As + t * 8);
        gl_lds16(Ap + 64 * DIM + k0, As + (t + 256) * 8);
        gl_lds16(Bp + k0,            Bs + t * 8);
        gl_lds16(Bp + 64 * DIM + k0, Bs + (t + 256) * 8);
        __syncthreads();
        short8 fa[4], fb[4];
#pragma unroll
        for (int mi = 0; mi < 4; ++mi)
            fa[mi] = *(const short8*)(As + (wm + mi * 16 + l15) * 32 + quad * 8);
#pragma unroll
        for (int ni = 0; ni < 4; ++ni)
            fb[ni] = *(const short8*)(Bs + (wn + ni * 16 + l15) * 32 + quad * 8);
#pragma unroll
        for (int mi = 0; mi < 4; ++mi)
#pragma unroll
            for (int ni = 0; ni < 4; ++ni)
                acc[mi][ni] = __builtin_amdgcn_mfma_f32_16x16x32_bf16(fa[mi], fb[ni], acc[mi][ni], 0, 0, 0);
    }
#pragma unroll
    for (int mi = 0; mi < 4; ++mi)
#pragma unroll
        for (int ni = 0; ni < 4; ++ni) {
            const int col = colT + wn + ni * 16 + l15;
            const float bb = (z == 0) ? bout[col] : 0.f;
#pragma unroll
            for (int r = 0; r < 4; ++r) {
                const int row = rowT + wm + mi * 16 + quad * 4 + r;
                if (row >= ROWS) continue;
                const int b = row / NTOK, n = row % NTOK;
                if (z == 0) {
                    dout[(size_t)row * DIM + col] = acc[mi][ni][r] + bb;
                } else if (n >= 1) {
                    dout[OUT0 + ((size_t)(b * (NTOK - 1) + (n - 1))) * DIM + col] = acc[mi][ni][r];
                }
            }
        }
}

extern "C" void kernel_launch(void* const* d_in, const int* in_sizes, int n_in,
                              void* d_out, int out_size, void* d_ws, size_t ws_size,
                              hipStream_t stream)
{
    const float* x    = (const float*)d_in[0];
    const float* mask = (const float*)d_in[1];
    const float* wqkv = (const float*)d_in[2];
    const float* wout = (const float*)d_in[3];
    const float* bout = (const float*)d_in[4];
    float* ws = (float*)d_ws;
    unsigned short* qkv16  = (unsigned short*)(ws + OFF_QKV16);
    unsigned short* qkvm16 = (unsigned short*)(ws + OFF_QKVM16);
    unsigned short* qe  = (unsigned short*)(ws + OFF_QE);
    unsigned short* ke  = (unsigned short*)(ws + OFF_KE);
    unsigned short* vt  = (unsigned short*)(ws + OFF_VT);
    unsigned short* abf = (unsigned short*)(ws + OFF_ABF);
    unsigned short* wq  = (unsigned short*)(ws + OFF_WQ);
    unsigned short* wo  = (unsigned short*)(ws + OFF_WO);
    float* cmax = ws + OFF_CMAX;
    float* upd  = ws + OFF_UPD;
    float* out  = (float*)d_out;

    hipMemsetAsync(cmax, 0, 9216 * sizeof(float), stream);
    hipLaunchKernelGGL(k_cvt,           dim3(1584, 1, 4), dim3(TPB), 0, stream, x, mask, wqkv, wout, abf, wq, wo);
    hipLaunchKernelGGL(k_gemm_qkv_mfma, dim3(18, 33, 2),  dim3(TPB), 0, stream, abf, wq, qkv16, qkvm16, cmax);
    hipLaunchKernelGGL(k_misc,          dim3(1073),       dim3(TPB), 0, stream, mask, upd, vt);
    hipLaunchKernelGGL(k_prep,          dim3(17, 12, 4),  dim3(TPB), 0, stream, qkv16, qkvm16, cmax, qe, ke, vt);
    hipLaunchKernelGGL(k_attn,          dim3(17, 48),     dim3(TPB), 0, stream, qe, ke, vt, upd, abf);
    hipLaunchKernelGGL(k_gemm_out_mfma, dim3(6, 33, 2),   dim3(TPB), 0, stream, abf, wo, bout, out);
}

// Round 8
// 248.216 us; speedup vs baseline: 1.1230x; 1.1230x over previous
//
#include <hip/hip_runtime.h>
#include <cmath>

#define TPB 256
#define ATPB 128

static const int NTOK  = 1025;
static const int DIM   = 768;
static const int HEADS = 12;
static const int QK3   = 2304;
static const int ROWS  = 4 * NTOK;        // 4100
static const int MROWS = 4 * (NTOK - 1);  // 4096
static const int MPAD  = 4224;            // 33*128 padded A rows
static const int NPAD  = 1088;            // 17*64
static const int VROWS = 129;             // 128 V cols + 1 ones-row (l column)
static const size_t OUT0 = (size_t)ROWS * DIM;
static const size_t APLANE = (size_t)MPAD * DIM;   // bf16 per plane

// workspace offsets in floats (qkv/qkvm bf16)
static const size_t OFF_QKV16  = 0;          // 4100*2304 u16 = 4,723,200 f
static const size_t OFF_QKVM16 = 4800000;    // 4096*2304 u16 = 4,718,592 f
static const size_t OFF_QE     = 9600000;    // 48*1088*64 u16 = 1,671,168 f
static const size_t OFF_KE     = 11300000;   // 1,671,168 f
static const size_t OFF_VT     = 13000000;   // 48*129*1088 u16 = 3,368,448 f
static const size_t OFF_ABF    = 16400000;   // 2*4224*768 u16 = 3,244,032 f
static const size_t OFF_WQ     = 19700000;   // 2*2304*768 u16 = 1,769,472 f
static const size_t OFF_WO     = 21500000;   // 2*768*768 u16  =   589,824 f
static const size_t OFF_CMAX   = 22100000;   // 9,216 f
static const size_t OFF_UPD    = 22110000;   // 4,100 f
// k_attn ones-group staging reads vt rows 129..143 of the last bh: lands in
// the VT->ABF gap (mapped, finite poison); those acc rows are never used.

typedef __attribute__((ext_vector_type(8))) short short8;
typedef __attribute__((ext_vector_type(4))) float f32x4;

__device__ __forceinline__ unsigned short f2bf(float f) {
    union { float f; unsigned int u; } c; c.f = f;
    unsigned int u = c.u + 0x7fffu + ((c.u >> 16) & 1u);  // RNE
    return (unsigned short)(u >> 16);
}
__device__ __forceinline__ float bf2f(unsigned short u) {
    union { unsigned int u; float f; } c; c.u = (unsigned int)u << 16;
    return c.f;
}
__device__ __forceinline__ void gl_lds16(const unsigned short* g, unsigned short* l) {
    __builtin_amdgcn_global_load_lds(
        (const __attribute__((address_space(1))) unsigned int*)g,
        (__attribute__((address_space(3))) unsigned int*)l, 16, 0, 0);
}

// ---------------------------------------------------------------------------
// K0: fp32 -> bf16 conversions (unchanged)
// ---------------------------------------------------------------------------
__global__ __launch_bounds__(TPB)
void k_cvt(const float* __restrict__ x, const float* __restrict__ mask,
           const float* __restrict__ wqkv, const float* __restrict__ wout,
           unsigned short* __restrict__ Abf, unsigned short* __restrict__ Wq,
           unsigned short* __restrict__ Wo)
{
    const int z = blockIdx.z;
    const size_t idx = ((size_t)blockIdx.x * TPB + threadIdx.x) * 8;
    unsigned short o[8] __attribute__((aligned(16)));
    if (z <= 1) {
        if (idx >= APLANE) return;
        const int row = (int)(idx / DIM);
        const int M = z ? MROWS : ROWS;
        const float* src = z ? mask : x;
        if (row < M) {
            float a[8];
            *(float4*)&a[0] = *(const float4*)(src + idx);
            *(float4*)&a[4] = *(const float4*)(src + idx + 4);
#pragma unroll
            for (int i = 0; i < 8; ++i) o[i] = f2bf(a[i]);
        } else {
#pragma unroll
            for (int i = 0; i < 8; ++i) o[i] = 0;
        }
        *(short8*)(Abf + (size_t)z * APLANE + idx) = *(short8*)o;
    } else {
        const size_t tot = (z == 2) ? (size_t)QK3 * DIM : (size_t)DIM * DIM;
        if (idx >= tot) return;
        const float* src = (z == 2) ? wqkv : wout;
        unsigned short* dst = (z == 2) ? Wq : Wo;
        float a[8];
        *(float4*)&a[0] = *(const float4*)(src + idx);
        *(float4*)&a[4] = *(const float4*)(src + idx + 4);
        unsigned short oa[8] __attribute__((aligned(16)));
#pragma unroll
        for (int i = 0; i < 8; ++i) { o[i] = f2bf(a[i]); oa[i] = f2bf(fabsf(a[i])); }
        *(short8*)(dst + idx) = *(short8*)o;
        *(short8*)(dst + tot + idx) = *(short8*)oa;
    }
}

// ---------------------------------------------------------------------------
// K1: bf16 MFMA GEMM, BK=64, bf16 C, fused col-max (unchanged)
// ---------------------------------------------------------------------------
__global__ __launch_bounds__(TPB)
void k_gemm_qkv_mfma(const unsigned short* __restrict__ Abf,
                     const unsigned short* __restrict__ Wq,
                     unsigned short* __restrict__ qkv16,
                     unsigned short* __restrict__ qkvm16,
                     float* __restrict__ cmax)
{
    const int z = blockIdx.z;
    const int rowT = blockIdx.y * 128, colT = blockIdx.x * 128;
    if (z == 1 && rowT >= MROWS) return;
    const unsigned short* A = Abf + (size_t)z * APLANE;
    const unsigned short* B = Wq + (size_t)z * QK3 * DIM;

    __shared__ unsigned short As[128 * 64];
    __shared__ unsigned short Bs[128 * 64];

    const int t = threadIdx.x;
    const int w = t >> 6, lane = t & 63, l15 = lane & 15, quad = lane >> 4;
    const int wm = (w & 1) * 64, wn = (w >> 1) * 64;
    const int sr = t >> 2, sk = (t & 3) * 8;

    f32x4 acc[4][4];
#pragma unroll
    for (int i = 0; i < 4; ++i)
#pragma unroll
        for (int j = 0; j < 4; ++j) acc[i][j] = (f32x4){0.f, 0.f, 0.f, 0.f};

    for (int k0 = 0; k0 < DIM; k0 += 64) {
        __syncthreads();
#pragma unroll
        for (int c = 0; c < 4; ++c) {
            const int gr = sr + (c & 1) * 64;
            const int gk = k0 + (c >> 1) * 32 + sk;
            gl_lds16(A + (size_t)(rowT + gr) * DIM + gk, As + c * 2048 + t * 8);
            gl_lds16(B + (size_t)(colT + gr) * DIM + gk, Bs + c * 2048 + t * 8);
        }
        __syncthreads();
        short8 fa[2][4], fb[2][4];
#pragma unroll
        for (int kk = 0; kk < 2; ++kk) {
#pragma unroll
            for (int mi = 0; mi < 4; ++mi)
                fa[kk][mi] = *(const short8*)(As + kk * 4096 + (wm + mi * 16 + l15) * 32 + quad * 8);
#pragma unroll
            for (int ni = 0; ni < 4; ++ni)
                fb[kk][ni] = *(const short8*)(Bs + kk * 4096 + (wn + ni * 16 + l15) * 32 + quad * 8);
        }
#pragma unroll
        for (int kk = 0; kk < 2; ++kk)
#pragma unroll
            for (int mi = 0; mi < 4; ++mi)
#pragma unroll
                for (int ni = 0; ni < 4; ++ni)
                    acc[mi][ni] = __builtin_amdgcn_mfma_f32_16x16x32_bf16(fa[kk][mi], fb[kk][ni], acc[mi][ni], 0, 0, 0);
    }

    float cm[4] = {0.f, 0.f, 0.f, 0.f};
#pragma unroll
    for (int mi = 0; mi < 4; ++mi)
#pragma unroll
        for (int ni = 0; ni < 4; ++ni) {
            const int col = colT + wn + ni * 16 + l15;
#pragma unroll
            for (int r = 0; r < 4; ++r) {
                const int row = rowT + wm + mi * 16 + quad * 4 + r;
                const float v = acc[mi][ni][r];
                if (z == 0) {
                    if (row < ROWS) qkv16[(size_t)row * QK3 + col] = f2bf(v);
                } else {
                    qkvm16[(size_t)row * QK3 + col] = f2bf(v);
                    cm[ni] = fmaxf(cm[ni], v);
                }
            }
        }
    if (z == 1) {
        const int bb = rowT >> 10;
#pragma unroll
        for (int ni = 0; ni < 4; ++ni) {
            float m = cm[ni];
            m = fmaxf(m, __shfl_xor(m, 16, 64));
            m = fmaxf(m, __shfl_xor(m, 32, 64));
            if (quad == 0)
                atomicMax((int*)&cmax[bb * QK3 + colT + wn + ni * 16 + l15], __float_as_int(m));
        }
    }
}

// ---------------------------------------------------------------------------
// K2: merged small kernels (unchanged)
// ---------------------------------------------------------------------------
__global__ __launch_bounds__(TPB)
void k_misc(const float* __restrict__ mask, float* __restrict__ upd,
            unsigned short* __restrict__ vt)
{
    const int bx = blockIdx.x;
    if (bx >= 1025) {
        const int bh = bx - 1025;
        unsigned short* p = vt + ((size_t)bh * VROWS + 128) * NPAD;
        for (int n = threadIdx.x; n < NPAD; n += TPB)
            p[n] = (n < NTOK) ? (unsigned short)0x3F80 : (unsigned short)0;
        return;
    }
    const int w = threadIdx.x >> 6, lane = threadIdx.x & 63;
    const int r = bx * 4 + w;
    if (r >= ROWS) return;
    const int b = r / NTOK, n = r % NTOK;
    float res = 1.f;
    if (n > 0) {
        const float* p = mask + (size_t)(b * (NTOK - 1) + (n - 1)) * DIM;
        float s = 0.f;
        for (int i = lane; i < DIM; i += 64) s += p[i];
#pragma unroll
        for (int off = 32; off > 0; off >>= 1) s += __shfl_xor(s, off, 64);
        res = (s > 0.f) ? 1.f : 0.f;
    }
    if (lane == 0) upd[r] = res;
}

// ---------------------------------------------------------------------------
// K3: qe/ke bf16 [bh,1088,64], vt bf16 transposed [bh,129,1088] (unchanged)
// ---------------------------------------------------------------------------
__global__ __launch_bounds__(TPB)
void k_prep(const unsigned short* __restrict__ qkv16,
            const unsigned short* __restrict__ qkvm16,
            const float* __restrict__ cmax, unsigned short* __restrict__ qe,
            unsigned short* __restrict__ ke, unsigned short* __restrict__ vt)
{
    __shared__ unsigned short Vt_l[128 * 66];
    const int t = threadIdx.x;
    const int nt = blockIdx.x, h = blockIdx.y, b = blockIdx.z;
    const int bh = b * HEADS + h;
    const int nl = t >> 2, ds0 = (t & 3) * 16;
    const int n = nt * 64 + nl;
    const bool valid = n < NTOK;
    const int col0 = h * 64 + ds0;

    unsigned short q16[16] __attribute__((aligned(16))) = {0};
    unsigned short k16[16] __attribute__((aligned(16))) = {0};
    unsigned short v16[16] __attribute__((aligned(16))) = {0};
    unsigned short qm16[16] __attribute__((aligned(16)));
    unsigned short km16[16] __attribute__((aligned(16)));
    unsigned short vm16[16] __attribute__((aligned(16)));
    float cq[16], ck[16], cv[16];

    const bool useM = valid && (n > 0);
    if (valid) {
        const size_t br = (size_t)(b * NTOK + n) * QK3 + col0;
        *(short8*)&q16[0] = *(const short8*)(qkv16 + br);
        *(short8*)&q16[8] = *(const short8*)(qkv16 + br + 8);
        *(short8*)&k16[0] = *(const short8*)(qkv16 + br + 768);
        *(short8*)&k16[8] = *(const short8*)(qkv16 + br + 776);
        *(short8*)&v16[0] = *(const short8*)(qkv16 + br + 1536);
        *(short8*)&v16[8] = *(const short8*)(qkv16 + br + 1544);
    }
    if (useM) {
        const size_t mr = (size_t)(b * 1024 + (n - 1)) * QK3 + col0;
        *(short8*)&qm16[0] = *(const short8*)(qkvm16 + mr);
        *(short8*)&qm16[8] = *(const short8*)(qkvm16 + mr + 8);
        *(short8*)&km16[0] = *(const short8*)(qkvm16 + mr + 768);
        *(short8*)&km16[8] = *(const short8*)(qkvm16 + mr + 776);
        *(short8*)&vm16[0] = *(const short8*)(qkvm16 + mr + 1536);
        *(short8*)&vm16[8] = *(const short8*)(qkvm16 + mr + 1544);
        const int cb = b * QK3 + col0;
#pragma unroll
        for (int i = 0; i < 4; ++i) {
            *(float4*)&cq[i * 4] = *(const float4*)(cmax + cb + i * 4);
            *(float4*)&ck[i * 4] = *(const float4*)(cmax + cb + 768 + i * 4);
            *(float4*)&cv[i * 4] = *(const float4*)(cmax + cb + 1536 + i * 4);
        }
    }

    unsigned short oq[16] __attribute__((aligned(16)));
    unsigned short ok[16] __attribute__((aligned(16)));
#pragma unroll
    for (int idx = 0; idx < 16; ++idx) {
        const float qm = useM ? bf2f(qm16[idx]) / (1e-6f + cq[idx]) : 1.f;
        const float km = useM ? bf2f(km16[idx]) / (1e-6f + ck[idx]) : 1.f;
        const float vm = valid ? (useM ? bf2f(vm16[idx]) / (1e-6f + cv[idx]) : 1.f) : 0.f;
        oq[idx] = f2bf(bf2f(q16[idx]) * qm * 0.125f);
        ok[idx] = f2bf(bf2f(k16[idx]) * km);
        const int d = ds0 + idx;
        Vt_l[d * 66 + nl]        = f2bf(bf2f(v16[idx]) * vm);
        Vt_l[(64 + d) * 66 + nl] = f2bf(vm);
    }
    if (valid) {
        unsigned short* qp = qe + ((size_t)bh * NPAD + n) * 64 + ds0;
        unsigned short* kp = ke + ((size_t)bh * NPAD + n) * 64 + ds0;
        *(short8*)qp       = *(short8*)oq;
        *(short8*)(qp + 8) = *(short8*)(oq + 8);
        *(short8*)kp       = *(short8*)ok;
        *(short8*)(kp + 8) = *(short8*)(ok + 8);
    }
    __syncthreads();
    const int c = t >> 1, nh = (t & 1) * 32;
    unsigned short ov[32] __attribute__((aligned(16)));
#pragma unroll
    for (int i = 0; i < 32; ++i) ov[i] = Vt_l[c * 66 + nh + i];
    unsigned short* vp = vt + ((size_t)bh * VROWS + c) * NPAD + nt * 64 + nh;
#pragma unroll
    for (int i = 0; i < 4; ++i) *(short8*)(vp + i * 8) = *(short8*)(ov + i * 8);
}

// ---------------------------------------------------------------------------
// K4: MFMA flash attention, operand-swapped, R6 gl_lds staging, with
// 2 q-tiles per wave: each staged K/V fragment is read from LDS ONCE and
// feeds TWO MFMAs (j=0,1) -> LDS-read traffic per FLOP halves (it was the
// dominant pipe: 26 ds_read_b128 for 26 MFMA, no reuse). Block = 2 waves
// covering 64 q; grid unchanged (17 x 48) for load balance.
// ---------------------------------------------------------------------------
__global__ __launch_bounds__(ATPB)
void k_attn(const unsigned short* __restrict__ qe, const unsigned short* __restrict__ ke,
            const unsigned short* __restrict__ vt, const float* __restrict__ upd,
            unsigned short* __restrict__ ab2)
{
    __shared__ short8 KsF[8 * 64];    // g = kk*4 + nc
    __shared__ short8 VsF[18 * 64];   // g = kk*9 + c8 (c8=8 is the ones-group)

    const int t = threadIdx.x;
    const int w = t >> 6, lane = t & 63;
    const int l15 = lane & 15, quad = lane >> 4;
    const int bh = blockIdx.y;
    const int b = bh / HEADS, h = bh % HEADS;
    const int q0 = blockIdx.x * 64;

    // two q-tiles per wave: j=0 -> rows q0+w*32+l15, j=1 -> +16
    short8 qf[2][2];
#pragma unroll
    for (int j = 0; j < 2; ++j) {
        const unsigned short* qp = qe + ((size_t)bh * NPAD + q0 + w * 32 + j * 16 + l15) * 64 + (quad << 3);
        qf[j][0] = *(const short8*)qp;
        qf[j][1] = *(const short8*)(qp + 32);
    }
    const int pA = (quad & 1) * 32 + l15;   // shuffle source lanes
    const int pB = pA + 16;
    const bool lo32 = (lane < 32);

    f32x4 acc[2][9];   // [j][0..7] = 128 out cols (d), [j][8] = l column
#pragma unroll
    for (int j = 0; j < 2; ++j)
#pragma unroll
        for (int g = 0; g < 9; ++g) acc[j][g] = (f32x4){0.f, 0.f, 0.f, 0.f};

    for (int kt = 0; kt < 17; ++kt) {
        const int kn0 = kt * 64;
        __syncthreads();
        // K stage: wave w -> groups 4w..4w+3
#pragma unroll
        for (int gi = 0; gi < 4; ++gi) {
            const int g = 4 * w + gi, kk = g >> 2, nc = g & 3;
            const unsigned short* gp = ke + ((size_t)bh * NPAD + kn0 + nc * 16 + l15) * 64
                                          + kk * 32 + (quad << 3);
            gl_lds16(gp, (unsigned short*)&KsF[g * 64] + lane * 8);
        }
        // V stage: wave w -> groups w, w+2, ..., w+16
#pragma unroll
        for (int i = 0; i < 9; ++i) {
            const int g = w + 2 * i;
            const int kk = (g >= 9) ? 1 : 0, c8 = g - kk * 9;
            const unsigned short* gp = vt + ((size_t)bh * VROWS + c8 * 16 + l15) * NPAD
                                          + kn0 + kk * 32 + (quad << 3);
            gl_lds16(gp, (unsigned short*)&VsF[g * 64] + lane * 8);
        }
        __syncthreads();

        // S^T: each K-frag read once, used for both q-tiles
        f32x4 s[2][4];
#pragma unroll
        for (int nc = 0; nc < 4; ++nc) {
            const short8 k0 = KsF[nc * 64 + lane];
            const short8 k1 = KsF[(4 + nc) * 64 + lane];
#pragma unroll
            for (int j = 0; j < 2; ++j) {
                f32x4 z = (f32x4){0.f, 0.f, 0.f, 0.f};
                z = __builtin_amdgcn_mfma_f32_16x16x32_bf16(k0, qf[j][0], z, 0, 0, 0);
                z = __builtin_amdgcn_mfma_f32_16x16x32_bf16(k1, qf[j][1], z, 0, 0, 0);
                s[j][nc] = z;
            }
        }
        // p = exp(S - 10) (exact softmax after final 1/l); pack + permute -> P^T B-frags
        short8 pf[2][2];
#pragma unroll
        for (int j = 0; j < 2; ++j) {
            unsigned int dA[4], dB[4];
#pragma unroll
            for (int nc = 0; nc < 4; ++nc) {
                const float p0 = __expf(s[j][nc][0] - 10.f);
                const float p1 = __expf(s[j][nc][1] - 10.f);
                const float p2 = __expf(s[j][nc][2] - 10.f);
                const float p3 = __expf(s[j][nc][3] - 10.f);
                dA[nc] = (unsigned int)f2bf(p0) | ((unsigned int)f2bf(p1) << 16);
                dB[nc] = (unsigned int)f2bf(p2) | ((unsigned int)f2bf(p3) << 16);
            }
            union { int i[4]; short8 s; } u0, u1;
            {
                const int a0 = __shfl((int)dA[0], pA, 64), a1 = __shfl((int)dA[1], pA, 64);
                const int b0 = __shfl((int)dB[0], pA, 64), b1 = __shfl((int)dB[1], pA, 64);
                const int a2 = __shfl((int)dA[0], pB, 64), a3 = __shfl((int)dA[1], pB, 64);
                const int b2 = __shfl((int)dB[0], pB, 64), b3 = __shfl((int)dB[1], pB, 64);
                u0.i[0] = lo32 ? a0 : a1;
                u0.i[1] = lo32 ? b0 : b1;
                u0.i[2] = lo32 ? a2 : a3;
                u0.i[3] = lo32 ? b2 : b3;
            }
            {
                const int a0 = __shfl((int)dA[2], pA, 64), a1 = __shfl((int)dA[3], pA, 64);
                const int b0 = __shfl((int)dB[2], pA, 64), b1 = __shfl((int)dB[3], pA, 64);
                const int a2 = __shfl((int)dA[2], pB, 64), a3 = __shfl((int)dA[3], pB, 64);
                const int b2 = __shfl((int)dB[2], pB, 64), b3 = __shfl((int)dB[3], pB, 64);
                u1.i[0] = lo32 ? a0 : a1;
                u1.i[1] = lo32 ? b0 : b1;
                u1.i[2] = lo32 ? a2 : a3;
                u1.i[3] = lo32 ? b2 : b3;
            }
            pf[j][0] = u0.s;
            pf[j][1] = u1.s;
        }
        // O^T += V^T P^T : each V-frag read once, used for both q-tiles
#pragma unroll
        for (int g = 0; g < 9; ++g) {
            const short8 v0 = VsF[g * 64 + lane];
            const short8 v1 = VsF[(9 + g) * 64 + lane];
#pragma unroll
            for (int j = 0; j < 2; ++j) {
                acc[j][g] = __builtin_amdgcn_mfma_f32_16x16x32_bf16(v0, pf[j][0], acc[j][g], 0, 0, 0);
                acc[j][g] = __builtin_amdgcn_mfma_f32_16x16x32_bf16(v1, pf[j][1], acc[j][g], 0, 0, 0);
            }
        }
    }

#pragma unroll
    for (int j = 0; j < 2; ++j) {
        // l(q) sits at quad==0, reg 0 of acc[j][8], lane l15 = q
        const float lq = __shfl(acc[j][8][0], l15, 64);
        const int qrow = q0 + w * 32 + j * 16 + l15;
        if (qrow < NTOK) {
            const size_t rg = (size_t)b * NTOK + qrow;
            const float inv = upd[rg] / lq;
#pragma unroll
            for (int g = 0; g < 8; ++g) {
                uint2 pk;
                pk.x = (unsigned int)f2bf(acc[j][g][0] * inv) | ((unsigned int)f2bf(acc[j][g][1] * inv) << 16);
                pk.y = (unsigned int)f2bf(acc[j][g][2] * inv) | ((unsigned int)f2bf(acc[j][g][3] * inv) << 16);
                const size_t addr = (size_t)(g >> 2) * APLANE + rg * DIM + h * 64 + (g & 3) * 16 + quad * 4;
                *(uint2*)(ab2 + addr) = pk;
            }
        }
    }
}

// ---------------------------------------------------------------------------
// K5: bf16 MFMA out-GEMMs (unchanged)
// ---------------------------------------------------------------------------
__global__ __launch_bounds__(TPB)
void k_gemm_out_mfma(const unsigned short* __restrict__ ab2,
                     const unsigned short* __restrict__ Wo,
                     const float* __restrict__ bout, float* __restrict__ dout)
{
    const int z = blockIdx.z;
    const unsigned short* A = ab2 + (size_t)z * APLANE;
    const unsigned short* B = Wo + (size_t)z * DIM * DIM;

    __shared__ unsigned short As[128 * 32];
    __shared__ unsigned short Bs[128 * 32];

    const int t = threadIdx.x;
    const int w = t >> 6, lane = t & 63, l15 = lane & 15, quad = lane >> 4;
    const int rowT = blockIdx.y * 128, colT = blockIdx.x * 128;
    const int wm = (w & 1) * 64, wn = (w >> 1) * 64;

    const int r0 = t >> 2, kc = (t & 3) * 8;
    const unsigned short* Ap = A + (size_t)(rowT + r0) * DIM + kc;
    const unsigned short* Bp = B + (size_t)(colT + r0) * DIM + kc;

    f32x4 acc[4][4];
#pragma unroll
    for (int i = 0; i < 4; ++i)
#pragma unroll
        for (int j = 0; j < 4; ++j) acc[i][j] = (f32x4){0.f, 0.f, 0.f, 0.f};

    for (int k0 = 0; k0 < DIM; k0 += 32) {
        __syncthreads();
        gl_lds16(Ap + k0,            As + t * 8);
        gl_lds16(Ap + 64 * DIM + k0, As + (t + 256) * 8);
        gl_lds16(Bp + k0,            Bs + t * 8);
        gl_lds16(Bp + 64 * DIM + k0, Bs + (t + 256) * 8);
        __syncthreads();
        short8 fa[4], fb[4];
#pragma unroll
        for (int mi = 0; mi < 4; ++mi)
            fa[mi] = *(const short8*)(As + (wm + mi * 16 + l15) * 32 + quad * 8);
#pragma unroll
        for (int ni = 0; ni < 4; ++ni)
            fb[ni] = *(const short8*)(Bs + (wn + ni * 16 + l15) * 32 + quad * 8);
#pragma unroll
        for (int mi = 0; mi < 4; ++mi)
#pragma unroll
            for (int ni = 0; ni < 4; ++ni)
                acc[mi][ni] = __builtin_amdgcn_mfma_f32_16x16x32_bf16(fa[mi], fb[ni], acc[mi][ni], 0, 0, 0);
    }
#pragma unroll
    for (int mi = 0; mi < 4; ++mi)
#pragma unroll
        for (int ni = 0; ni < 4; ++ni) {
            const int col = colT + wn + ni * 16 + l15;
            const float bb = (z == 0) ? bout[col] : 0.f;
#pragma unroll
            for (int r = 0; r < 4; ++r) {
                const int row = rowT + wm + mi * 16 + quad * 4 + r;
                if (row >= ROWS) continue;
                const int b = row / NTOK, n = row % NTOK;
                if (z == 0) {
                    dout[(size_t)row * DIM + col] = acc[mi][ni][r] + bb;
                } else if (n >= 1) {
                    dout[OUT0 + ((size_t)(b * (NTOK - 1) + (n - 1))) * DIM + col] = acc[mi][ni][r];
                }
            }
        }
}

extern "C" void kernel_launch(void* const* d_in, const int* in_sizes, int n_in,
                              void* d_out, int out_size, void* d_ws, size_t ws_size,
                              hipStream_t stream)
{
    const float* x    = (const float*)d_in[0];
    const float* mask = (const float*)d_in[1];
    const float* wqkv = (const float*)d_in[2];
    const float* wout = (const float*)d_in[3];
    const float* bout = (const float*)d_in[4];
    float* ws = (float*)d_ws;
    unsigned short* qkv16  = (unsigned short*)(ws + OFF_QKV16);
    unsigned short* qkvm16 = (unsigned short*)(ws + OFF_QKVM16);
    unsigned short* qe  = (unsigned short*)(ws + OFF_QE);
    unsigned short* ke  = (unsigned short*)(ws + OFF_KE);
    unsigned short* vt  = (unsigned short*)(ws + OFF_VT);
    unsigned short* abf = (unsigned short*)(ws + OFF_ABF);
    unsigned short* wq  = (unsigned short*)(ws + OFF_WQ);
    unsigned short* wo  = (unsigned short*)(ws + OFF_WO);
    float* cmax = ws + OFF_CMAX;
    float* upd  = ws + OFF_UPD;
    float* out  = (float*)d_out;

    hipMemsetAsync(cmax, 0, 9216 * sizeof(float), stream);
    hipLaunchKernelGGL(k_cvt,           dim3(1584, 1, 4), dim3(TPB), 0, stream, x, mask, wqkv, wout, abf, wq, wo);
    hipLaunchKernelGGL(k_gemm_qkv_mfma, dim3(18, 33, 2),  dim3(TPB), 0, stream, abf, wq, qkv16, qkvm16, cmax);
    hipLaunchKernelGGL(k_misc,          dim3(1073),       dim3(TPB), 0, stream, mask, upd, vt);
    hipLaunchKernelGGL(k_prep,          dim3(17, 12, 4),  dim3(TPB), 0, stream, qkv16, qkvm16, cmax, qe, ke, vt);
    hipLaunchKernelGGL(k_attn,          dim3(17, 48),     dim3(ATPB), 0, stream, qe, ke, vt, upd, abf);
    hipLaunchKernelGGL(k_gemm_out_mfma, dim3(6, 33, 2),   dim3(TPB), 0, stream, abf, wo, bout, out);
}